// Round 1
// baseline (368.949 us; speedup 1.0000x reference)
//
#include <hip/hip_runtime.h>

#define B_ 16
#define C_ 64
#define H_ 64
#define W_ 64
#define K_ 1024
#define HW_ (H_*W_)              // 4096
#define N_ (B_*HW_)              // 65536 pixels
#define NELEM (B_*C_*HW_)        // 4194304 output elements

// ---------------- kernel 1: codebook norms + zero the loss accumulator ----
__global__ __launch_bounds__(256) void vq_prep(const float* __restrict__ emb,
                                               float* __restrict__ e2,
                                               float* __restrict__ acc) {
    int k = blockIdx.x * blockDim.x + threadIdx.x;
    if (k == 0) *acc = 0.0f;
    if (k < K_) {
        const float* row = emb + k * C_;
        float s0 = 0.f, s1 = 0.f, s2 = 0.f, s3 = 0.f;
        #pragma unroll
        for (int c = 0; c < C_; c += 4) {
            s0 = fmaf(row[c+0], row[c+0], s0);
            s1 = fmaf(row[c+1], row[c+1], s1);
            s2 = fmaf(row[c+2], row[c+2], s2);
            s3 = fmaf(row[c+3], row[c+3], s3);
        }
        e2[k] = (s0 + s1) + (s2 + s3);
    }
}

// ---------------- kernel 2: per-pixel argmin over K codes -----------------
// Block = 256 threads = 4 waves. Block owns 64 pixels (one per lane).
// Wave w scans K-quadrant [w*256, w*256+256) -> emb addresses are
// wave-uniform (scalar-load path). Cross-wave combine via LDS with
// first-index tie-break (lower wave = lower k range, strict <).
__global__ __launch_bounds__(256) void vq_argmin(const float* __restrict__ z,
                                                 const float* __restrict__ emb,
                                                 const float* __restrict__ e2,
                                                 int* __restrict__ idx_out) {
    __shared__ float sdist[4][64];
    __shared__ int   sidx[4][64];

    const int lane = threadIdx.x & 63;
    const int wave = __builtin_amdgcn_readfirstlane(threadIdx.x >> 6);

    const int n  = blockIdx.x * 64 + lane;   // pixel id (block-aligned, b fixed)
    const int b  = n >> 12;                  // / 4096
    const int hw = n & 4095;

    // z vector for this pixel: stride HW_ between channels, coalesced across lanes
    const float* zp = z + (size_t)b * C_ * HW_ + hw;
    float zv[C_];
    #pragma unroll
    for (int c = 0; c < C_; ++c) zv[c] = zp[(size_t)c * HW_];

    const int kbase = wave * (K_ / 4);
    float best  = 3.4e38f;
    int   bestk = kbase;

    for (int kk = 0; kk < K_ / 4; ++kk) {
        const int k = kbase + kk;            // wave-uniform
        const float* er = emb + (size_t)k * C_;
        float d0 = 0.f, d1 = 0.f, d2 = 0.f, d3 = 0.f;
        #pragma unroll
        for (int c = 0; c < C_; c += 4) {
            d0 = fmaf(zv[c+0], er[c+0], d0);
            d1 = fmaf(zv[c+1], er[c+1], d1);
            d2 = fmaf(zv[c+2], er[c+2], d2);
            d3 = fmaf(zv[c+3], er[c+3], d3);
        }
        const float dot  = (d0 + d1) + (d2 + d3);
        const float dist = fmaf(-2.0f, dot, e2[k]);
        if (dist < best) { best = dist; bestk = k; }
    }

    sdist[wave][lane] = best;
    sidx [wave][lane] = bestk;
    __syncthreads();

    if (threadIdx.x < 64) {
        float bb = sdist[0][lane];
        int   bi = sidx [0][lane];
        #pragma unroll
        for (int w2 = 1; w2 < 4; ++w2) {
            float d = sdist[w2][lane];
            if (d < bb) { bb = d; bi = sidx[w2][lane]; }
        }
        idx_out[blockIdx.x * 64 + lane] = bi;
    }
}

// ---------------- kernel 3: gather q, write q_st, accumulate (q-z)^2 ------
__global__ __launch_bounds__(256) void vq_output(const float* __restrict__ z,
                                                 const float* __restrict__ emb,
                                                 const int* __restrict__ idx,
                                                 float* __restrict__ out,
                                                 float* __restrict__ acc) {
    const int o  = blockIdx.x * 256 + threadIdx.x;   // index in [B,C,H,W] layout
    const int hw = o & 4095;
    const int bc = o >> 12;
    const int c  = bc & 63;
    const int b  = bc >> 6;
    const int n  = b * HW_ + hw;

    const float zval = z[o];
    const float q    = emb[(size_t)idx[n] * C_ + c];
    const float diff = q - zval;              // matches reference op order
    out[o] = zval + diff;                     // q_st = z + (q - z)

    float sq = diff * diff;
    #pragma unroll
    for (int off = 32; off; off >>= 1) sq += __shfl_xor(sq, off);

    __shared__ float red[4];
    if ((threadIdx.x & 63) == 0) red[threadIdx.x >> 6] = sq;
    __syncthreads();
    if (threadIdx.x == 0) {
        atomicAdd(acc, (red[0] + red[1]) + (red[2] + red[3]));
    }
}

// ---------------- kernel 4: finalize loss ---------------------------------
__global__ void vq_finalize(const float* __restrict__ acc, float* __restrict__ out) {
    // loss = q_latent + 0.25*e_latent, both equal mean((q-z)^2) in value
    out[NELEM] = 1.25f * (*acc) / (float)NELEM;
}

extern "C" void kernel_launch(void* const* d_in, const int* in_sizes, int n_in,
                              void* d_out, int out_size, void* d_ws, size_t ws_size,
                              hipStream_t stream) {
    const float* z   = (const float*)d_in[0];   // [16,64,64,64]
    const float* emb = (const float*)d_in[1];   // [1024,64]
    float* out = (float*)d_out;                 // [4194304 q_st] ++ [1 loss]

    float* acc = (float*)d_ws;                  // 1 float (loss accumulator)
    float* e2  = acc + 64;                      // 1024 floats
    int*   idx = (int*)(e2 + K_);               // 65536 ints

    vq_prep    <<<(K_ + 255) / 256, 256, 0, stream>>>(emb, e2, acc);
    vq_argmin  <<<N_ / 64,          256, 0, stream>>>(z, emb, e2, idx);
    vq_output  <<<NELEM / 256,      256, 0, stream>>>(z, emb, idx, out, acc);
    vq_finalize<<<1, 1, 0, stream>>>(acc, out);
}

// Round 2
// 50.494 us; speedup vs baseline: 7.3068x; 7.3068x over previous
//
#include <hip/hip_runtime.h>

#define B_ 16
#define C_ 64
#define HW_ 4096              // H*W
#define K_ 1024
#define N_ 65536              // B*H*W pixels
#define NELEM 4194304         // B*C*H*W

typedef __attribute__((ext_vector_type(8))) short bf16x8;
typedef __attribute__((ext_vector_type(4))) float f32x4;

static __device__ __forceinline__ short f2bf(float f) {
    union { float f; unsigned u; } v; v.f = f;
    unsigned r = v.u + 0x7fffu + ((v.u >> 16) & 1u);   // RNE
    return (short)(r >> 16);
}

// ---------------- kernel 1: codebook squared norms ------------------------
__global__ __launch_bounds__(256) void vq_prep(const float* __restrict__ emb,
                                               float* __restrict__ e2) {
    int k = blockIdx.x * blockDim.x + threadIdx.x;
    if (k < K_) {
        const float4* row = (const float4*)(emb + (size_t)k * C_);
        float s0 = 0.f, s1 = 0.f, s2 = 0.f, s3 = 0.f;
        #pragma unroll
        for (int i = 0; i < C_ / 4; ++i) {
            float4 v = row[i];
            s0 = fmaf(v.x, v.x, s0);
            s1 = fmaf(v.y, v.y, s1);
            s2 = fmaf(v.z, v.z, s2);
            s3 = fmaf(v.w, v.w, s3);
        }
        e2[k] = (s0 + s1) + (s2 + s3);
    }
}

// ---------------- kernel 2: fused MFMA argmin + gather + q_st + loss ------
// Block = 256 thr = 4 waves, owns 64 consecutive pixels (same b, hw0..hw0+63).
// Wave w scans K-quadrant [w*256, w*256+256) with mfma_f32_16x16x32_bf16:
//   A = 16-code tile (lane supplies emb[code = base+(l&15)][k = ks*32+8*(l>>4)+j])
//   B = 16-pixel tile (lane supplies z[pixel = pt*16+(l&15)][same k])
//   D[row=code = (l>>4)*4+r][col=pixel = l&15]   (m89-verified layout)
__global__ __launch_bounds__(256) void vq_main(const float* __restrict__ z,
                                               const float* __restrict__ emb,
                                               const float* __restrict__ e2,
                                               float* __restrict__ out,
                                               float* __restrict__ psum) {
    __shared__ float sdist[4][64];
    __shared__ int   sidx[4][64];
    __shared__ int   cidx[64];
    __shared__ float red[4];

    const int tid  = threadIdx.x;
    const int lane = tid & 63;
    const int wave = __builtin_amdgcn_readfirstlane(tid >> 6);
    const int prow = lane & 15;        // pixel-in-tile / code-in-tile (A row)
    const int kgrp = lane >> 4;        // k-group 0..3

    const int blk = blockIdx.x;        // 0..1023
    const int b   = blk >> 6;          // 64 blocks per image
    const int hw0 = (blk & 63) * 64;
    const float* zp = z + (size_t)b * C_ * HW_ + hw0;   // + c*HW_ + p

    // ---- load z fragments (B operand), bf16 ----
    bf16x8 zf[4][2];
    #pragma unroll
    for (int pt = 0; pt < 4; ++pt) {
        const int p = pt * 16 + prow;
        #pragma unroll
        for (int ks = 0; ks < 2; ++ks) {
            const int d0 = ks * 32 + kgrp * 8;
            bf16x8 f;
            #pragma unroll
            for (int j = 0; j < 8; ++j)
                f[j] = f2bf(zp[(size_t)(d0 + j) * HW_ + p]);
            zf[pt][ks] = f;
        }
    }

    // ---- per-wave argmin over its 256-code quadrant ----
    const int kq = wave * 256;
    float best[4];
    int   bestk[4];
    #pragma unroll
    for (int pt = 0; pt < 4; ++pt) { best[pt] = 3.4e38f; bestk[pt] = kq; }

    for (int ct = 0; ct < 16; ++ct) {
        const int code_a = kq + ct * 16 + prow;           // A-frag row
        const float* er = emb + (size_t)code_a * C_ + kgrp * 8;
        bf16x8 af0, af1;
        #pragma unroll
        for (int j = 0; j < 8; ++j) {
            af0[j] = f2bf(er[j]);
            af1[j] = f2bf(er[32 + j]);
        }
        const int kcode = kq + ct * 16 + kgrp * 4;        // my 4 D-rows
        const float4 e2v = *(const float4*)(e2 + kcode);

        #pragma unroll
        for (int pt = 0; pt < 4; ++pt) {
            f32x4 acc = {0.f, 0.f, 0.f, 0.f};
            acc = __builtin_amdgcn_mfma_f32_16x16x32_bf16(af0, zf[pt][0], acc, 0, 0, 0);
            acc = __builtin_amdgcn_mfma_f32_16x16x32_bf16(af1, zf[pt][1], acc, 0, 0, 0);
            #pragma unroll
            for (int r = 0; r < 4; ++r) {
                const float e2r = (r == 0) ? e2v.x : (r == 1) ? e2v.y : (r == 2) ? e2v.z : e2v.w;
                const float dist = fmaf(-2.0f, acc[r], e2r);
                if (dist < best[pt]) { best[pt] = dist; bestk[pt] = kcode + r; }
            }
        }
    }

    // cross-lane combine over k-groups (bits 4,5 of lane)
    #pragma unroll
    for (int pt = 0; pt < 4; ++pt) {
        #pragma unroll
        for (int m = 16; m <= 32; m <<= 1) {
            const float od = __shfl_xor(best[pt], m);
            const int   ok = __shfl_xor(bestk[pt], m);
            if (od < best[pt] || (od == best[pt] && ok < bestk[pt])) {
                best[pt] = od; bestk[pt] = ok;
            }
        }
        if (kgrp == 0) {
            sdist[wave][pt * 16 + prow] = best[pt];
            sidx [wave][pt * 16 + prow] = bestk[pt];
        }
    }
    __syncthreads();

    // cross-wave combine (wave = ascending k quadrants)
    if (tid < 64) {
        float bb = sdist[0][tid];
        int   bi = sidx [0][tid];
        #pragma unroll
        for (int w2 = 1; w2 < 4; ++w2) {
            const float d = sdist[w2][tid];
            const int   k = sidx [w2][tid];
            if (d < bb || (d == bb && k < bi)) { bb = d; bi = k; }
        }
        cidx[tid] = bi;
    }
    __syncthreads();

    // ---- output phase: q_st = z + (q - z), partial loss ----
    float* op = out + (size_t)b * C_ * HW_ + hw0;
    const int p  = tid & 63;
    const int c0 = tid >> 6;
    const float* qrow = emb + (size_t)cidx[p] * C_;
    float sq = 0.f;
    #pragma unroll
    for (int i = 0; i < 16; ++i) {
        const int c = c0 * 16 + i;
        const float zv   = zp[(size_t)c * HW_ + p];
        const float q    = qrow[c];
        const float diff = q - zv;
        op[(size_t)c * HW_ + p] = zv + diff;
        sq = fmaf(diff, diff, sq);
    }
    #pragma unroll
    for (int off = 32; off; off >>= 1) sq += __shfl_xor(sq, off);
    if (lane == 0) red[wave] = sq;
    __syncthreads();
    if (tid == 0) psum[blk] = (red[0] + red[1]) + (red[2] + red[3]);
}

// ---------------- kernel 3: reduce partials -> loss -----------------------
__global__ __launch_bounds__(256) void vq_finalize(const float* __restrict__ psum,
                                                   float* __restrict__ out) {
    const int tid = threadIdx.x;
    float s = 0.f;
    #pragma unroll
    for (int i = 0; i < 4; ++i) s += psum[i * 256 + tid];
    #pragma unroll
    for (int off = 32; off; off >>= 1) s += __shfl_xor(s, off);
    __shared__ float red[4];
    if ((tid & 63) == 0) red[tid >> 6] = s;
    __syncthreads();
    if (tid == 0)
        out[NELEM] = 1.25f * ((red[0] + red[1]) + (red[2] + red[3])) / (float)NELEM;
}

extern "C" void kernel_launch(void* const* d_in, const int* in_sizes, int n_in,
                              void* d_out, int out_size, void* d_ws, size_t ws_size,
                              hipStream_t stream) {
    const float* z   = (const float*)d_in[0];   // [16,64,64,64]
    const float* emb = (const float*)d_in[1];   // [1024,64]
    float* out = (float*)d_out;                 // [4194304 q_st] ++ [1 loss]

    float* psum = (float*)d_ws;                 // 1024 floats
    float* e2   = psum + K_;                    // 1024 floats

    vq_prep    <<<K_ / 256, 256, 0, stream>>>(emb, e2);
    vq_main    <<<N_ / 64,  256, 0, stream>>>(z, emb, e2, out, psum);
    vq_finalize<<<1,        256, 0, stream>>>(psum, out);
}